// Round 19
// baseline (334.817 us; speedup 1.0000x reference)
//
#include <hip/hip_runtime.h>
#include <cstdint>
#include <cstddef>

#define BATCH  4
#define RUNITS 128
#define MM     5
#define SEG    128            // c per b-segment
#define MS     512            // fp8 mirror row stride bytes (4 segs x 128)
#define KB     672            // GEMM K: 20 sub-steps (m*128+c) + 1 tail sub-step

typedef unsigned int  uint32;
typedef unsigned char uchar;
typedef unsigned short ushort16;
typedef __attribute__((ext_vector_type(8))) short short8;
typedef __attribute__((ext_vector_type(4))) float f32x4;
typedef __attribute__((ext_vector_type(2))) float f32x2;

__device__ inline ushort16 f2bf(float f){
  uint32 u = __float_as_uint(f);
  return (ushort16)((u + 0x7FFFu + ((u >> 16) & 1u)) >> 16);
}
__device__ inline uint32 packbf(float a, float b){
  return (uint32)f2bf(a) | ((uint32)f2bf(b) << 16);
}
__device__ inline float bf2f(ushort16 v){ return __uint_as_float(((uint32)v) << 16); }
__device__ inline int sw4(int r){ return (r ^ (r >> 2)) & 3; }

__device__ inline uint32 pk4f8(float a, float b, float c, float d){
  uint32 w = __builtin_amdgcn_cvt_pk_fp8_f32(a, b, 0u, false);
  w = __builtin_amdgcn_cvt_pk_fp8_f32(c, d, w, true);
  return w;
}
__device__ inline uchar f8(float a){
  return (uchar)(__builtin_amdgcn_cvt_pk_fp8_f32(a, 0.f, 0u, false) & 0xFFu);
}
__device__ inline uint4 f8x8_to_bf8(uint2 u8){
  f32x2 p0 = __builtin_amdgcn_cvt_pk_f32_fp8(u8.x, false);
  f32x2 p1 = __builtin_amdgcn_cvt_pk_f32_fp8(u8.x, true);
  f32x2 p2 = __builtin_amdgcn_cvt_pk_f32_fp8(u8.y, false);
  f32x2 p3 = __builtin_amdgcn_cvt_pk_f32_fp8(u8.y, true);
  uint4 r;
  r.x = packbf(p0.x, p0.y); r.y = packbf(p1.x, p1.y);
  r.z = packbf(p2.x, p2.y); r.w = packbf(p3.x, p3.y);
  return r;
}

// async global -> LDS, 16B/lane
__device__ inline void gld16(const void* g, void* l) {
  __builtin_amdgcn_global_load_lds(
      (const __attribute__((address_space(1))) unsigned int*)g,
      (__attribute__((address_space(3))) unsigned int*)l, 16, 0, 0);
}

// ---------------- graph prep ----------------

__global__ void k_zero_i(int* p, int n) {
  int i = blockIdx.x*blockDim.x + threadIdx.x;
  if (i < n) p[i] = 0;
}

__global__ void k_deg_cnt(const int* __restrict__ src, const int* __restrict__ dst,
                          const float* __restrict__ w, int E,
                          float* deg_out, float* deg_in, int* cnt_f, int* cnt_b) {
  int e = blockIdx.x*blockDim.x + threadIdx.x;
  if (e >= E) return;
  int s = src[e], d = dst[e]; float we = w[e];
  atomicAdd(&deg_out[s], we);
  atomicAdd(&deg_in[d], we);
  atomicAdd(&cnt_f[s], 1);
  atomicAdd(&cnt_b[d], 1);
}

__global__ __launch_bounds__(256) void k_scansum(
    const int* __restrict__ cnt_f, const int* __restrict__ cnt_b, int* bsum, int n) {
  const int* cnt = blockIdx.y ? cnt_b : cnt_f;
  int tid = threadIdx.x, lane = tid & 63, wv = tid >> 6;
  int i = blockIdx.x*256 + tid;
  int v = (i < n) ? cnt[i] : 0;
  #pragma unroll
  for (int d = 32; d > 0; d >>= 1) v += __shfl_down(v, d);
  __shared__ int sm[4];
  if (lane == 0) sm[wv] = v;
  __syncthreads();
  if (tid == 0) bsum[blockIdx.y*40 + blockIdx.x] = sm[0]+sm[1]+sm[2]+sm[3];
}

__global__ __launch_bounds__(64) void k_scanmid(
    const int* bsum, int* bofs, int* ptrF, int* ptrB, int n, int nb) {
  int lane = threadIdx.x;
  for (int a = 0; a < 2; ++a) {
    int v = (lane < nb) ? bsum[a*nb + lane] : 0;
    int x = v;
    #pragma unroll
    for (int d = 1; d < 64; d <<= 1) { int t = __shfl_up(x, d); if (lane >= d) x += t; }
    if (lane < nb) bofs[a*nb + lane] = x - v;
    if (lane == nb - 1) { if (a) ptrB[n] = x; else ptrF[n] = x; }
  }
}

__global__ __launch_bounds__(256) void k_scanapply(
    const int* __restrict__ cnt_f, const int* __restrict__ cnt_b, const int* __restrict__ bofs,
    int* ptrF, int* curF, int* ptrB, int* curB, int n) {
  int a = blockIdx.y;
  const int* cnt = a ? cnt_b : cnt_f;
  int* ptr = a ? ptrB : ptrF;
  int* cur = a ? curB : curF;
  int tid = threadIdx.x, lane = tid & 63, wv = tid >> 6;
  int i = blockIdx.x*256 + tid;
  int v = (i < n) ? cnt[i] : 0;
  int x = v;
  #pragma unroll
  for (int d = 1; d < 64; d <<= 1) { int t = __shfl_up(x, d); if (lane >= d) x += t; }
  __shared__ int ws[4];
  __shared__ int wo[4];
  if (lane == 63) ws[wv] = x;
  __syncthreads();
  if (tid == 0) { int s = 0; for (int k = 0; k < 4; ++k) { wo[k] = s; s += ws[k]; } }
  __syncthreads();
  int excl = x - v + wo[wv] + bofs[a*40 + blockIdx.x];
  if (i < n) { ptr[i] = excl; cur[i] = excl; }
}

__global__ void k_fill(const int* __restrict__ src, const int* __restrict__ dst,
                       const float* __restrict__ w, int E,
                       const float* __restrict__ deg_out, const float* __restrict__ deg_in,
                       int* cur_f, int* cur_b,
                       int* col_f, float* val_f, int* col_b, float* val_b) {
  int e = blockIdx.x*blockDim.x + threadIdx.x;
  if (e >= E) return;
  int s = src[e], d = dst[e]; float we = w[e];
  int pf = atomicAdd(&cur_f[s], 1);
  col_f[pf] = d; val_f[pf] = we / deg_out[s];
  int pb = atomicAdd(&cur_b[d], 1);
  col_b[pb] = s; val_b[pb] = we / deg_in[d];
}

// ---------------- weight pack (both matrices, one launch) ----------------

__global__ void k_packw2(const float* __restrict__ Wg, const float* __restrict__ Wc,
                         ushort16* __restrict__ WtG, ushort16* __restrict__ WtC) {
  int idx = blockIdx.x*blockDim.x + threadIdx.x;
  const int tg = 2*RUNITS*KB;
  const int tc = RUNITS*KB;
  if (idx >= tg + tc) return;
  const float* W; ushort16* Wt; int ncol;
  if (idx < tg) { W = Wg; Wt = WtG; ncol = 2*RUNITS; }
  else { idx -= tg; W = Wc; Wt = WtC; ncol = RUNITS; }
  int o = idx / KB, k = idx - o*KB;
  float v = 0.f;
  if (k < 640) {
    int m = k >> 7, c = k & 127;
    v = W[(size_t)(c*MM + m)*ncol + o];
  } else if (k < 645) {
    v = W[(size_t)k*ncol + o];
  }
  Wt[idx] = f2bf(v);
}

// ---------------- build x0 -> mirror slot 0 + tails ----------------

__global__ __launch_bounds__(256) void k_build_x0(
    const float* __restrict__ inp, const float* __restrict__ hf,
    uchar* __restrict__ mA0, ushort16* __restrict__ xtail,
    uchar* __restrict__ tl8, int N) {
  int wv = threadIdx.x >> 6, lane = threadIdx.x & 63;
  int n = blockIdx.x*4 + wv;
  if (n >= N) return;
  int b = lane >> 4, ch = lane & 15;
  size_t r = (size_t)b*N + n;
  size_t hbase = r*RUNITS;
  float fv[8];
  if (ch == 0) {
    fv[0] = inp[r];
    #pragma unroll
    for (int s = 1; s < 8; ++s) fv[s] = hf[hbase + s - 1];
  } else {
    int c0 = ch*8 - 1;
    #pragma unroll
    for (int s = 0; s < 8; ++s) fv[s] = hf[hbase + c0 + s];
  }
  uint2 mv;
  mv.x = pk4f8(fv[0], fv[1], fv[2], fv[3]);
  mv.y = pk4f8(fv[4], fv[5], fv[6], fv[7]);
  *(uint2*)(mA0 + (size_t)n*MS + b*128 + ch*8) = mv;
  if (ch == 15) {
    float h127 = hf[hbase + 127];
    xtail[((size_t)n*4 + b)*16 + 0] = f2bf(h127);
    tl8[(size_t)(0*4 + b)*N + n] = f8(h127);
  }
}

// ---------------- full-wave dual SPMM over fp8 mirrors (fp8 in, fp8 out) ----------------

template<bool HY>
__global__ __launch_bounds__(256) void k_spmm2(
    const int* __restrict__ ptrF, const int* __restrict__ colF, const float* __restrict__ valF,
    const int* __restrict__ ptrB, const int* __restrict__ colB, const float* __restrict__ valB,
    const uchar* __restrict__ minF, const uchar* __restrict__ minB,
    uchar* __restrict__ moutF, uchar* __restrict__ moutB,
    const uchar* __restrict__ mY0, ushort16* __restrict__ xtail,
    uchar* __restrict__ tl8,
    int tinF, int tinB, int toutF, int toutB, int tz,
    int N, int sgrid, float alpha, float beta) {
  int bid = blockIdx.x;
  bool jb = bid >= sgrid;
  const int* ptr = jb ? ptrB : ptrF;
  const int* col = jb ? colB : colF;
  const float* val = jb ? valB : valF;
  const uchar* M = jb ? minB : minF;
  uchar* mout = jb ? moutB : moutF;
  int tin = jb ? tinB : tinF;
  int tout = jb ? toutB : toutF;
  int wv = threadIdx.x >> 6, lane = threadIdx.x & 63;
  int n = (bid - (jb ? sgrid : 0))*4 + wv;
  if (n >= N) return;
  int s = ptr[n], e = ptr[n+1];
  bool tq = lane < 4;
  const uchar* tlin = tl8 + (size_t)(tin*4 + lane)*N;
  float a[8] = {0.f,0.f,0.f,0.f,0.f,0.f,0.f,0.f};
  float at = 0.f;
  #pragma unroll 8
  for (int i = s; i < e; ++i) {
    int cl = col[i]; float v = val[i];
    uint2 u = *(const uint2*)(M + (size_t)cl*MS + lane*8);
    f32x2 p0 = __builtin_amdgcn_cvt_pk_f32_fp8(u.x, false);
    f32x2 p1 = __builtin_amdgcn_cvt_pk_f32_fp8(u.x, true);
    f32x2 p2 = __builtin_amdgcn_cvt_pk_f32_fp8(u.y, false);
    f32x2 p3 = __builtin_amdgcn_cvt_pk_f32_fp8(u.y, true);
    a[0] += v*p0.x; a[1] += v*p0.y;
    a[2] += v*p1.x; a[3] += v*p1.y;
    a[4] += v*p2.x; a[5] += v*p2.y;
    a[6] += v*p3.x; a[7] += v*p3.y;
    if (tq) {
      uint32 tb = tlin[cl];
      at += v * __builtin_amdgcn_cvt_f32_fp8(tb, 0);
    }
  }
  float r[8];
  if (HY) {
    uint2 y8 = *(const uint2*)(mY0 + (size_t)n*MS + lane*8);
    f32x2 y0 = __builtin_amdgcn_cvt_pk_f32_fp8(y8.x, false);
    f32x2 y1 = __builtin_amdgcn_cvt_pk_f32_fp8(y8.x, true);
    f32x2 y2 = __builtin_amdgcn_cvt_pk_f32_fp8(y8.y, false);
    f32x2 y3 = __builtin_amdgcn_cvt_pk_f32_fp8(y8.y, true);
    r[0] = alpha*a[0] + beta*y0.x; r[1] = alpha*a[1] + beta*y0.y;
    r[2] = alpha*a[2] + beta*y1.x; r[3] = alpha*a[3] + beta*y1.y;
    r[4] = alpha*a[4] + beta*y2.x; r[5] = alpha*a[5] + beta*y2.y;
    r[6] = alpha*a[6] + beta*y3.x; r[7] = alpha*a[7] + beta*y3.y;
  } else {
    #pragma unroll
    for (int k = 0; k < 8; ++k) r[k] = alpha*a[k];
  }
  uint2 mv;
  mv.x = pk4f8(r[0], r[1], r[2], r[3]);
  mv.y = pk4f8(r[4], r[5], r[6], r[7]);
  *(uint2*)(mout + (size_t)n*MS + lane*8) = mv;
  if (tq) {
    float rt = alpha*at;
    if (HY) rt += beta * bf2f(xtail[((size_t)n*4 + lane)*16 + tz]);
    xtail[((size_t)n*4 + lane)*16 + tout] = f2bf(rt);
    tl8[(size_t)(tout*4 + lane)*N + n] = f8(rt);
  }
}

// ---------------- unified MFMA GEMM: BK=64 (2 sub-steps per barrier) ----------------
// mlv: 6 mirror slots; A staged per sub-step: fp8 load -> cvt -> swizzled ds_write.
// 11 barriers instead of 21. MODE 0 (gates, grid.y=2): sigmoid; by=0 -> r*hx into
// slot5 + tails; by=1 -> ub. MODE 1 (cand, l0slot=5): tanh + GRU + fused projection.

template<int TM, int MODE>
__global__ __launch_bounds__(256, 4) void k_gemm(
    const uchar* __restrict__ mlv, const ushort16* __restrict__ xtail,
    const ushort16* __restrict__ Bt, const float* __restrict__ bias,
    const float* __restrict__ hx, const float* __restrict__ inp,
    uchar* __restrict__ mB0, ushort16* __restrict__ xtw, uchar* __restrict__ tl8,
    ushort16* __restrict__ ub, float* __restrict__ outh,
    float* __restrict__ outy, const float* __restrict__ wpj,
    const float* __restrict__ bpj, int l0slot, int N, int BN) {
  constexpr int NI = TM / 32;
  __shared__ __align__(16) ushort16 As[2][2][TM*32];
  __shared__ __align__(16) ushort16 Bs[2][2][128*32];
  __shared__ float pjl[TM][2];
  int tid = threadIdx.x, lane = tid & 63, wv = tid >> 6;
  int wm = wv >> 1, wn = wv & 1;
  int fr = lane & 15, g = lane >> 4;
  int R0 = blockIdx.x*TM, by = blockIdx.y;
  const size_t lvls = (size_t)N*MS;

  // --- A reg staging mapping (one chunk per thread per sub-step) ---
  int rA = tid >> 2, p = tid & 3;
  bool aact = (TM == 64) || (tid < TM*4);
  int sa = p ^ sw4(rA);
  int gr = R0 + rA; if (gr >= BN) gr = BN - 1;
  int bA = gr / N, nA = gr - bA*N;
  const uchar* aAnchor = mlv + (size_t)nA*MS + bA*128;
  const uchar* aM0 = aAnchor + (size_t)l0slot*lvls;
  const ushort16* tBase = xtail + ((size_t)nA*4 + bA)*16 + (MODE == 1 ? 8 : 0);
  int aofs = rA*32 + (p << 3);

  // --- B gload mapping: 2 instrs/wave per sub-step ---
  int colB0 = (wv*2 + 0)*16 + (lane >> 2);
  int colB1 = (wv*2 + 1)*16 + (lane >> 2);
  int posB  = lane & 3;
  const ushort16* bG0 = Bt + (size_t)(by*128 + colB0)*KB + (posB ^ sw4(colB0))*8;
  const ushort16* bG1 = Bt + (size_t)(by*128 + colB1)*KB + (posB ^ sw4(colB1))*8;

  f32x4 acc[NI][4];
  #pragma unroll
  for (int i = 0; i < NI; ++i)
    #pragma unroll
    for (int j = 0; j < 4; ++j) acc[i][j] = (f32x4){0.f,0.f,0.f,0.f};

  auto stageB = [&](int s, int bb, int h) {
    gld16(bG0 + 4*s*8, &Bs[bb][h][(wv*2 + 0)*512]);
    gld16(bG1 + 4*s*8, &Bs[bb][h][(wv*2 + 1)*512]);
  };
  auto stageA = [&](int s, int bb, int h) {
    if (!aact) return;
    if (s < 20) {
      int m = s >> 2;
      const uchar* base = (m == 0) ? aM0 : (aAnchor + (size_t)m*lvls);
      int ch = (4*s + sa) & 15;
      *(uint4*)&As[bb][h][aofs] = f8x8_to_bf8(*(const uint2*)(base + ch*8));
    } else {
      if (sa == 0) *(uint4*)&As[bb][h][aofs] = *(const uint4*)tBase;
    }
  };

  stageA(0, 0, 0); stageB(0, 0, 0);
  stageA(1, 0, 1); stageB(1, 0, 1);

  int buf = 0;
  for (int ss = 0; ss < 11; ++ss) {
    __syncthreads();              // staging for sub-steps {2ss, 2ss+1} complete
    if (ss < 10) {
      int s0 = 2*ss + 2, s1 = 2*ss + 3;
      stageB(s0, buf ^ 1, 0); stageA(s0, buf ^ 1, 0);
      if (s1 <= 20) { stageB(s1, buf ^ 1, 1); stageA(s1, buf ^ 1, 1); }
    }
    #pragma unroll
    for (int h = 0; h < 2; ++h) {
      if (ss == 10 && h == 1) continue;   // sub-step 21 doesn't exist
      short8 af[NI], bfv[4];
      #pragma unroll
      for (int i = 0; i < NI; ++i) {
        int rr = wm*(NI*16) + i*16 + fr;
        af[i] = *(const short8*)&As[buf][h][rr*32 + ((g ^ sw4(rr)) << 3)];
      }
      #pragma unroll
      for (int j = 0; j < 4; ++j) {
        int cc = wn*64 + j*16 + fr;
        bfv[j] = *(const short8*)&Bs[buf][h][cc*32 + ((g ^ sw4(cc)) << 3)];
      }
      #pragma unroll
      for (int i = 0; i < NI; ++i)
        #pragma unroll
        for (int j = 0; j < 4; ++j)
          acc[i][j] = __builtin_amdgcn_mfma_f32_16x16x32_bf16(af[i], bfv[j], acc[i][j], 0, 0, 0);
    }
    buf ^= 1;
  }

  #pragma unroll
  for (int i = 0; i < NI; ++i) {
    #pragma unroll
    for (int q2 = 0; q2 < 4; ++q2) {
      int row = R0 + wm*(NI*16) + i*16 + g*4 + q2;
      bool rok = row < BN;
      if (MODE == 0) {
        if (!rok) continue;
        int b2 = row / N, n2 = row - b2*N;
        #pragma unroll
        for (int j = 0; j < 4; ++j) {
          int o = wn*64 + j*16 + fr;
          float gv = acc[i][j][q2] + bias[by*128 + o];
          float sg = 1.f/(1.f + expf(-gv));
          if (by == 0) {
            float rv = sg * hx[(size_t)row*RUNITS + o];
            if (o < 127) {
              mB0[(size_t)n2*MS + b2*128 + o + 1] = f8(rv);
            } else {
              xtw[((size_t)n2*4 + b2)*16 + 8] = f2bf(rv);
              tl8[(size_t)(8*4 + b2)*N + n2] = f8(rv);
            }
            if (o == 0) mB0[(size_t)n2*MS + b2*128] = f8(inp[row]);
          } else {
            ub[(size_t)row*RUNITS + o] = f2bf(sg);
          }
        }
      } else {
        float pj = 0.f;
        #pragma unroll
        for (int j = 0; j < 4; ++j) {
          int o = wn*64 + j*16 + fr;
          float gv = acc[i][j][q2] + bias[o];
          float cv = tanhf(gv);
          if (rok) {
            float uu = bf2f(ub[(size_t)row*RUNITS + o]);
            float hh = hx[(size_t)row*RUNITS + o];
            float nh = uu*hh + (1.f - uu)*cv;
            outh[(size_t)row*RUNITS + o] = nh;
            pj += nh * wpj[o];
          }
        }
        #pragma unroll
        for (int d = 1; d < 16; d <<= 1) pj += __shfl_xor(pj, d);
        if (rok && fr == 0) pjl[row - R0][wn] = pj;
      }
    }
  }
  if (MODE == 1) {
    __syncthreads();
    if (tid < TM) {
      int row = R0 + tid;
      if (row < BN) outy[row] = pjl[tid][0] + pjl[tid][1] + bpj[0];
    }
  }
}

// ---------------- launcher ----------------

extern "C" void kernel_launch(void* const* d_in, const int* in_sizes, int n_in,
                              void* d_out, int out_size, void* d_ws, size_t ws_size,
                              hipStream_t stream) {
  const float* inputs = (const float*)d_in[0];
  const float* hidden = (const float*)d_in[1];
  const int*   esrc   = (const int*)d_in[2];
  const int*   edst   = (const int*)d_in[3];
  const float* ew     = (const float*)d_in[4];
  const float* Wg     = (const float*)d_in[5];
  const float* bg     = (const float*)d_in[6];
  const float* Wc     = (const float*)d_in[7];
  const float* bc     = (const float*)d_in[8];
  const float* Wpj    = (const float*)d_in[9];
  const float* bpj    = (const float*)d_in[10];

  const int N  = in_sizes[0] / BATCH;
  const int E  = in_sizes[2];
  const int BN = BATCH * N;

  char* p = (char*)d_ws;
  auto alloc = [&](size_t bytes) -> void* {
    void* r = (void*)p;
    p += (bytes + 255) & ~(size_t)255;
    return r;
  };

  float* deg_out = (float*)alloc((size_t)4*N*sizeof(float));
  float* deg_in  = deg_out + N;
  int*   cnt_f   = (int*)(deg_out + 2*(size_t)N);
  int*   cnt_b   = cnt_f + N;
  int*   ptr_f   = (int*)alloc((size_t)(N+1)*sizeof(int));
  int*   ptr_b   = (int*)alloc((size_t)(N+1)*sizeof(int));
  int*   cur_f   = (int*)alloc((size_t)N*sizeof(int));
  int*   cur_b   = (int*)alloc((size_t)N*sizeof(int));
  int*   col_f   = (int*)alloc((size_t)E*sizeof(int));
  int*   col_b   = (int*)alloc((size_t)E*sizeof(int));
  float* val_f   = (float*)alloc((size_t)E*sizeof(float));
  float* val_b   = (float*)alloc((size_t)E*sizeof(float));
  int*   bsum    = (int*)alloc(80*sizeof(int));
  int*   bofs    = (int*)alloc(80*sizeof(int));
  ushort16* WtG  = (ushort16*)alloc((size_t)2*RUNITS*KB*sizeof(ushort16));
  ushort16* WtC  = (ushort16*)alloc((size_t)RUNITS*KB*sizeof(ushort16));
  uchar* mlv     = (uchar*)alloc((size_t)6*N*MS);   // slots 0..5
  ushort16* xtail= (ushort16*)alloc((size_t)N*4*16*sizeof(ushort16));
  uchar* tl8     = (uchar*)alloc((size_t)16*4*N);
  ushort16* ub   = (ushort16*)alloc((size_t)BN*RUNITS*sizeof(ushort16));

  float* out_y = (float*)d_out;
  float* out_h = out_y + BN;

  const size_t lvls = (size_t)N*MS;
  uchar* mA0 = mlv;
  uchar* m1  = mlv + 1*lvls;
  uchar* m2  = mlv + 2*lvls;
  uchar* m3  = mlv + 3*lvls;
  uchar* m4  = mlv + 4*lvls;
  uchar* mB0 = mlv + 5*lvls;

  const int TB = 256;
  int nb = (N + 255)/256;
  k_zero_i<<<(4*N+TB-1)/TB, TB, 0, stream>>>((int*)deg_out, 4*N);
  k_deg_cnt<<<(E+TB-1)/TB, TB, 0, stream>>>(esrc, edst, ew, E, deg_out, deg_in, cnt_f, cnt_b);
  k_scansum<<<dim3(nb,2), TB, 0, stream>>>(cnt_f, cnt_b, bsum, N);
  k_scanmid<<<1, 64, 0, stream>>>(bsum, bofs, ptr_f, ptr_b, N, nb);
  k_scanapply<<<dim3(nb,2), TB, 0, stream>>>(cnt_f, cnt_b, bofs, ptr_f, cur_f, ptr_b, cur_b, N);
  k_fill<<<(E+TB-1)/TB, TB, 0, stream>>>(esrc, edst, ew, E, deg_out, deg_in,
                                         cur_f, cur_b, col_f, val_f, col_b, val_b);
  {
    int tot = 3*RUNITS*KB;
    k_packw2<<<(tot+TB-1)/TB, TB, 0, stream>>>(Wg, Wc, WtG, WtC);
  }

  int sgrid = (N + 3) / 4;
  int gx64 = (BN + 63) / 64;
  int gx32 = (BN + 31) / 32;

  // ---- gates gconv ----
  k_build_x0<<<sgrid, TB, 0, stream>>>(inputs, hidden, mA0, xtail, tl8, N);
  k_spmm2<false><<<2*sgrid, TB, 0, stream>>>(
      ptr_f, col_f, val_f, ptr_b, col_b, val_b,
      mA0, mA0, m1, m3, mA0, xtail, tl8,
      0, 0, 1, 3, 0, N, sgrid, 1.f, 0.f);
  k_spmm2<true><<<2*sgrid, TB, 0, stream>>>(
      ptr_f, col_f, val_f, ptr_b, col_b, val_b,
      m1, m3, m2, m4, mA0, xtail, tl8,
      1, 3, 2, 4, 0, N, sgrid, 2.f, -1.f);
  // gates GEMM: ub (by=1); mB0 = fp8 [x_in, r*hx] + tails (by=0)
  k_gemm<64, 0><<<dim3(gx64, 2), TB, 0, stream>>>(
      mlv, xtail, WtG, bg, hidden, inputs, mB0, xtail, tl8, ub,
      nullptr, nullptr, nullptr, nullptr, 0, N, BN);

  // ---- candidate gconv (level 0 = slot 5) ----
  k_spmm2<false><<<2*sgrid, TB, 0, stream>>>(
      ptr_f, col_f, val_f, ptr_b, col_b, val_b,
      mB0, mB0, m1, m3, mB0, xtail, tl8,
      8, 8, 9, 11, 8, N, sgrid, 1.f, 0.f);
  k_spmm2<true><<<2*sgrid, TB, 0, stream>>>(
      ptr_f, col_f, val_f, ptr_b, col_b, val_b,
      m1, m3, m2, m4, mB0, xtail, tl8,
      9, 11, 10, 12, 8, N, sgrid, 2.f, -1.f);
  k_gemm<32, 1><<<dim3(gx32, 1), TB, 0, stream>>>(
      mlv, xtail, WtC, bc, hidden, nullptr, nullptr, nullptr, nullptr, ub,
      out_h, out_y, Wpj, bpj, 5, N, BN);
}

// Round 20
// 311.066 us; speedup vs baseline: 1.0764x; 1.0764x over previous
//
#include <hip/hip_runtime.h>
#include <cstdint>
#include <cstddef>

#define BATCH  4
#define RUNITS 128
#define MM     5
#define SEG    128            // c per b-segment
#define MS     512            // fp8 mirror row stride bytes (4 segs x 128)
#define KB     672            // GEMM K: 20 steps (m*128+c) + 1 tail step

typedef unsigned int  uint32;
typedef unsigned char uchar;
typedef unsigned short ushort16;
typedef __attribute__((ext_vector_type(8))) short short8;
typedef __attribute__((ext_vector_type(4))) float f32x4;
typedef __attribute__((ext_vector_type(2))) float f32x2;

__device__ inline ushort16 f2bf(float f){
  uint32 u = __float_as_uint(f);
  return (ushort16)((u + 0x7FFFu + ((u >> 16) & 1u)) >> 16);
}
__device__ inline uint32 packbf(float a, float b){
  return (uint32)f2bf(a) | ((uint32)f2bf(b) << 16);
}
__device__ inline float bf2f(ushort16 v){ return __uint_as_float(((uint32)v) << 16); }
__device__ inline int sw4(int r){ return (r ^ (r >> 2)) & 3; }

__device__ inline uint32 pk4f8(float a, float b, float c, float d){
  uint32 w = __builtin_amdgcn_cvt_pk_fp8_f32(a, b, 0u, false);
  w = __builtin_amdgcn_cvt_pk_fp8_f32(c, d, w, true);
  return w;
}
__device__ inline uchar f8(float a){
  return (uchar)(__builtin_amdgcn_cvt_pk_fp8_f32(a, 0.f, 0u, false) & 0xFFu);
}
__device__ inline uint4 f8x8_to_bf8(uint2 u8){
  f32x2 p0 = __builtin_amdgcn_cvt_pk_f32_fp8(u8.x, false);
  f32x2 p1 = __builtin_amdgcn_cvt_pk_f32_fp8(u8.x, true);
  f32x2 p2 = __builtin_amdgcn_cvt_pk_f32_fp8(u8.y, false);
  f32x2 p3 = __builtin_amdgcn_cvt_pk_f32_fp8(u8.y, true);
  uint4 r;
  r.x = packbf(p0.x, p0.y); r.y = packbf(p1.x, p1.y);
  r.z = packbf(p2.x, p2.y); r.w = packbf(p3.x, p3.y);
  return r;
}

// async global -> LDS, 16B/lane
__device__ inline void gld16(const void* g, void* l) {
  __builtin_amdgcn_global_load_lds(
      (const __attribute__((address_space(1))) unsigned int*)g,
      (__attribute__((address_space(3))) unsigned int*)l, 16, 0, 0);
}

// ---------------- graph prep ----------------

__global__ void k_zero_i(int* p, int n) {
  int i = blockIdx.x*blockDim.x + threadIdx.x;
  if (i < n) p[i] = 0;
}

__global__ void k_deg_cnt(const int* __restrict__ src, const int* __restrict__ dst,
                          const float* __restrict__ w, int E,
                          float* deg_out, float* deg_in, int* cnt_f, int* cnt_b) {
  int e = blockIdx.x*blockDim.x + threadIdx.x;
  if (e >= E) return;
  int s = src[e], d = dst[e]; float we = w[e];
  atomicAdd(&deg_out[s], we);
  atomicAdd(&deg_in[d], we);
  atomicAdd(&cnt_f[s], 1);
  atomicAdd(&cnt_b[d], 1);
}

__global__ __launch_bounds__(256) void k_scansum(
    const int* __restrict__ cnt_f, const int* __restrict__ cnt_b, int* bsum, int n) {
  const int* cnt = blockIdx.y ? cnt_b : cnt_f;
  int tid = threadIdx.x, lane = tid & 63, wv = tid >> 6;
  int i = blockIdx.x*256 + tid;
  int v = (i < n) ? cnt[i] : 0;
  #pragma unroll
  for (int d = 32; d > 0; d >>= 1) v += __shfl_down(v, d);
  __shared__ int sm[4];
  if (lane == 0) sm[wv] = v;
  __syncthreads();
  if (tid == 0) bsum[blockIdx.y*40 + blockIdx.x] = sm[0]+sm[1]+sm[2]+sm[3];
}

__global__ __launch_bounds__(64) void k_scanmid(
    const int* bsum, int* bofs, int* ptrF, int* ptrB, int n, int nb) {
  int lane = threadIdx.x;
  for (int a = 0; a < 2; ++a) {
    int v = (lane < nb) ? bsum[a*nb + lane] : 0;
    int x = v;
    #pragma unroll
    for (int d = 1; d < 64; d <<= 1) { int t = __shfl_up(x, d); if (lane >= d) x += t; }
    if (lane < nb) bofs[a*nb + lane] = x - v;
    if (lane == nb - 1) { if (a) ptrB[n] = x; else ptrF[n] = x; }
  }
}

__global__ __launch_bounds__(256) void k_scanapply(
    const int* __restrict__ cnt_f, const int* __restrict__ cnt_b, const int* __restrict__ bofs,
    int* ptrF, int* curF, int* ptrB, int* curB, int n) {
  int a = blockIdx.y;
  const int* cnt = a ? cnt_b : cnt_f;
  int* ptr = a ? ptrB : ptrF;
  int* cur = a ? curB : curF;
  int tid = threadIdx.x, lane = tid & 63, wv = tid >> 6;
  int i = blockIdx.x*256 + tid;
  int v = (i < n) ? cnt[i] : 0;
  int x = v;
  #pragma unroll
  for (int d = 1; d < 64; d <<= 1) { int t = __shfl_up(x, d); if (lane >= d) x += t; }
  __shared__ int ws[4];
  __shared__ int wo[4];
  if (lane == 63) ws[wv] = x;
  __syncthreads();
  if (tid == 0) { int s = 0; for (int k = 0; k < 4; ++k) { wo[k] = s; s += ws[k]; } }
  __syncthreads();
  int excl = x - v + wo[wv] + bofs[a*40 + blockIdx.x];
  if (i < n) { ptr[i] = excl; cur[i] = excl; }
}

__global__ void k_fill(const int* __restrict__ src, const int* __restrict__ dst,
                       const float* __restrict__ w, int E,
                       const float* __restrict__ deg_out, const float* __restrict__ deg_in,
                       int* cur_f, int* cur_b,
                       int* col_f, float* val_f, int* col_b, float* val_b) {
  int e = blockIdx.x*blockDim.x + threadIdx.x;
  if (e >= E) return;
  int s = src[e], d = dst[e]; float we = w[e];
  int pf = atomicAdd(&cur_f[s], 1);
  col_f[pf] = d; val_f[pf] = we / deg_out[s];
  int pb = atomicAdd(&cur_b[d], 1);
  col_b[pb] = s; val_b[pb] = we / deg_in[d];
}

// ---------------- fused: build x0 (blocks < sgrid) + weight pack (rest) ----------------
// build: mirror slot 0 + tails; pack: WtG then WtC, k<640 -> (m,c), 640..644 tail, else 0

__global__ __launch_bounds__(256) void k_bx0pack(
    const float* __restrict__ inp, const float* __restrict__ hf,
    uchar* __restrict__ mA0, ushort16* __restrict__ xtail, uchar* __restrict__ tl8,
    const float* __restrict__ Wg, const float* __restrict__ Wc,
    ushort16* __restrict__ WtG, ushort16* __restrict__ WtC,
    int N, int sgrid) {
  if (blockIdx.x < (unsigned)sgrid) {
    int wv = threadIdx.x >> 6, lane = threadIdx.x & 63;
    int n = blockIdx.x*4 + wv;
    if (n >= N) return;
    int b = lane >> 4, ch = lane & 15;
    size_t r = (size_t)b*N + n;
    size_t hbase = r*RUNITS;
    float fv[8];
    if (ch == 0) {
      fv[0] = inp[r];
      #pragma unroll
      for (int s = 1; s < 8; ++s) fv[s] = hf[hbase + s - 1];
    } else {
      int c0 = ch*8 - 1;
      #pragma unroll
      for (int s = 0; s < 8; ++s) fv[s] = hf[hbase + c0 + s];
    }
    uint2 mv;
    mv.x = pk4f8(fv[0], fv[1], fv[2], fv[3]);
    mv.y = pk4f8(fv[4], fv[5], fv[6], fv[7]);
    *(uint2*)(mA0 + (size_t)n*MS + b*128 + ch*8) = mv;
    if (ch == 15) {
      float h127 = hf[hbase + 127];
      xtail[((size_t)n*4 + b)*16 + 0] = f2bf(h127);
      tl8[(size_t)(0*4 + b)*N + n] = f8(h127);
    }
  } else {
    int idx = (blockIdx.x - sgrid)*256 + threadIdx.x;
    const int tg = 2*RUNITS*KB;
    const int tc = RUNITS*KB;
    if (idx >= tg + tc) return;
    const float* W; ushort16* Wt; int ncol;
    if (idx < tg) { W = Wg; Wt = WtG; ncol = 2*RUNITS; }
    else { idx -= tg; W = Wc; Wt = WtC; ncol = RUNITS; }
    int o = idx / KB, k = idx - o*KB;
    float v = 0.f;
    if (k < 640) {
      int m = k >> 7, c = k & 127;
      v = W[(size_t)(c*MM + m)*ncol + o];
    } else if (k < 645) {
      v = W[(size_t)k*ncol + o];
    }
    Wt[idx] = f2bf(v);
  }
}

// ---------------- full-wave dual SPMM over fp8 mirrors (fp8 in, fp8 out) ----------------

template<bool HY>
__global__ __launch_bounds__(256) void k_spmm2(
    const int* __restrict__ ptrF, const int* __restrict__ colF, const float* __restrict__ valF,
    const int* __restrict__ ptrB, const int* __restrict__ colB, const float* __restrict__ valB,
    const uchar* __restrict__ minF, const uchar* __restrict__ minB,
    uchar* __restrict__ moutF, uchar* __restrict__ moutB,
    const uchar* __restrict__ mY0, ushort16* __restrict__ xtail,
    uchar* __restrict__ tl8,
    int tinF, int tinB, int toutF, int toutB, int tz,
    int N, int sgrid, float alpha, float beta) {
  int bid = blockIdx.x;
  bool jb = bid >= sgrid;
  const int* ptr = jb ? ptrB : ptrF;
  const int* col = jb ? colB : colF;
  const float* val = jb ? valB : valF;
  const uchar* M = jb ? minB : minF;
  uchar* mout = jb ? moutB : moutF;
  int tin = jb ? tinB : tinF;
  int tout = jb ? toutB : toutF;
  int wv = threadIdx.x >> 6, lane = threadIdx.x & 63;
  int n = (bid - (jb ? sgrid : 0))*4 + wv;
  if (n >= N) return;
  int s = ptr[n], e = ptr[n+1];
  bool tq = lane < 4;
  const uchar* tlin = tl8 + (size_t)(tin*4 + lane)*N;
  float a[8] = {0.f,0.f,0.f,0.f,0.f,0.f,0.f,0.f};
  float at = 0.f;
  #pragma unroll 8
  for (int i = s; i < e; ++i) {
    int cl = col[i]; float v = val[i];
    uint2 u = *(const uint2*)(M + (size_t)cl*MS + lane*8);
    f32x2 p0 = __builtin_amdgcn_cvt_pk_f32_fp8(u.x, false);
    f32x2 p1 = __builtin_amdgcn_cvt_pk_f32_fp8(u.x, true);
    f32x2 p2 = __builtin_amdgcn_cvt_pk_f32_fp8(u.y, false);
    f32x2 p3 = __builtin_amdgcn_cvt_pk_f32_fp8(u.y, true);
    a[0] += v*p0.x; a[1] += v*p0.y;
    a[2] += v*p1.x; a[3] += v*p1.y;
    a[4] += v*p2.x; a[5] += v*p2.y;
    a[6] += v*p3.x; a[7] += v*p3.y;
    if (tq) {
      uint32 tb = tlin[cl];
      at += v * __builtin_amdgcn_cvt_f32_fp8(tb, 0);
    }
  }
  float r[8];
  if (HY) {
    uint2 y8 = *(const uint2*)(mY0 + (size_t)n*MS + lane*8);
    f32x2 y0 = __builtin_amdgcn_cvt_pk_f32_fp8(y8.x, false);
    f32x2 y1 = __builtin_amdgcn_cvt_pk_f32_fp8(y8.x, true);
    f32x2 y2 = __builtin_amdgcn_cvt_pk_f32_fp8(y8.y, false);
    f32x2 y3 = __builtin_amdgcn_cvt_pk_f32_fp8(y8.y, true);
    r[0] = alpha*a[0] + beta*y0.x; r[1] = alpha*a[1] + beta*y0.y;
    r[2] = alpha*a[2] + beta*y1.x; r[3] = alpha*a[3] + beta*y1.y;
    r[4] = alpha*a[4] + beta*y2.x; r[5] = alpha*a[5] + beta*y2.y;
    r[6] = alpha*a[6] + beta*y3.x; r[7] = alpha*a[7] + beta*y3.y;
  } else {
    #pragma unroll
    for (int k = 0; k < 8; ++k) r[k] = alpha*a[k];
  }
  uint2 mv;
  mv.x = pk4f8(r[0], r[1], r[2], r[3]);
  mv.y = pk4f8(r[4], r[5], r[6], r[7]);
  *(uint2*)(mout + (size_t)n*MS + lane*8) = mv;
  if (tq) {
    float rt = alpha*at;
    if (HY) rt += beta * bf2f(xtail[((size_t)n*4 + lane)*16 + tz]);
    xtail[((size_t)n*4 + lane)*16 + tout] = f2bf(rt);
    tl8[(size_t)(tout*4 + lane)*N + n] = f8(rt);
  }
}

// ---------------- unified MFMA GEMM (all-fp8 A; B via global_load_lds) ----------------
// mlv: 6 mirror slots (stride N*MS): 0 = gconv1 level0, 1..4 = diffusion levels,
// 5 = gconv2 level0. A staged per step: fp8 load -> cvt -> swizzled ds_write.
// MODE 0 (gates, grid.y=2): sigmoid; by=0 -> r*hx into slot5 + tails; by=1 -> ub.
// MODE 1 (cand, l0slot=5): tanh + GRU combine + fused projection.

template<int TM, int MODE>
__global__ __launch_bounds__(256, 5) void k_gemm(
    const uchar* __restrict__ mlv, const ushort16* __restrict__ xtail,
    const ushort16* __restrict__ Bt, const float* __restrict__ bias,
    const float* __restrict__ hx, const float* __restrict__ inp,
    uchar* __restrict__ mB0, ushort16* __restrict__ xtw, uchar* __restrict__ tl8,
    ushort16* __restrict__ ub, float* __restrict__ outh,
    float* __restrict__ outy, const float* __restrict__ wpj,
    const float* __restrict__ bpj, int l0slot, int N, int BN) {
  constexpr int NI = TM / 32;
  __shared__ __align__(16) ushort16 As[2][TM*32];
  __shared__ __align__(16) ushort16 Bs[2][128*32];
  __shared__ float pjl[TM][2];
  int tid = threadIdx.x, lane = tid & 63, wv = tid >> 6;
  int wm = wv >> 1, wn = wv & 1;
  int fr = lane & 15, g = lane >> 4;
  int R0 = blockIdx.x*TM, by = blockIdx.y;
  const size_t lvls = (size_t)N*MS;

  // --- A reg staging mapping (one chunk per thread) ---
  int rA = tid >> 2, p = tid & 3;
  bool aact = (TM == 64) || (tid < TM*4);
  int sa = p ^ sw4(rA);
  int gr = R0 + rA; if (gr >= BN) gr = BN - 1;
  int bA = gr / N, nA = gr - bA*N;
  const uchar* aAnchor = mlv + (size_t)nA*MS + bA*128;
  const uchar* aM0 = aAnchor + (size_t)l0slot*lvls;
  const ushort16* tBase = xtail + ((size_t)nA*4 + bA)*16 + (MODE == 1 ? 8 : 0);
  int aofs = rA*32 + (p << 3);

  // --- B gload mapping: 2 instrs/wave, lane -> slot (col,pos) ---
  int colB0 = (wv*2 + 0)*16 + (lane >> 2);
  int colB1 = (wv*2 + 1)*16 + (lane >> 2);
  int posB  = lane & 3;
  const ushort16* bG0 = Bt + (size_t)(by*128 + colB0)*KB + (posB ^ sw4(colB0))*8;
  const ushort16* bG1 = Bt + (size_t)(by*128 + colB1)*KB + (posB ^ sw4(colB1))*8;

  f32x4 acc[NI][4];
  #pragma unroll
  for (int i = 0; i < NI; ++i)
    #pragma unroll
    for (int j = 0; j < 4; ++j) acc[i][j] = (f32x4){0.f,0.f,0.f,0.f};

  auto stageB = [&](int s, int bb) {
    gld16(bG0 + 4*s*8, &Bs[bb][(wv*2 + 0)*512]);
    gld16(bG1 + 4*s*8, &Bs[bb][(wv*2 + 1)*512]);
  };
  auto stageA = [&](int s, int bb) {
    if (!aact) return;
    if (s < 20) {
      int m = s >> 2;
      const uchar* base = (m == 0) ? aM0 : (aAnchor + (size_t)m*lvls);
      int ch = (4*s + sa) & 15;
      *(uint4*)&As[bb][aofs] = f8x8_to_bf8(*(const uint2*)(base + ch*8));
    } else {
      if (sa == 0) *(uint4*)&As[bb][aofs] = *(const uint4*)tBase;
    }
  };

  stageA(0, 0);
  stageB(0, 0);

  int buf = 0;
  for (int s = 0; s < 21; ++s) {
    __syncthreads();
    if (s < 20) { stageB(s + 1, buf ^ 1); stageA(s + 1, buf ^ 1); }
    short8 af[NI], bfv[4];
    #pragma unroll
    for (int i = 0; i < NI; ++i) {
      int rr = wm*(NI*16) + i*16 + fr;
      af[i] = *(const short8*)&As[buf][rr*32 + ((g ^ sw4(rr)) << 3)];
    }
    #pragma unroll
    for (int j = 0; j < 4; ++j) {
      int cc = wn*64 + j*16 + fr;
      bfv[j] = *(const short8*)&Bs[buf][cc*32 + ((g ^ sw4(cc)) << 3)];
    }
    #pragma unroll
    for (int i = 0; i < NI; ++i)
      #pragma unroll
      for (int j = 0; j < 4; ++j)
        acc[i][j] = __builtin_amdgcn_mfma_f32_16x16x32_bf16(af[i], bfv[j], acc[i][j], 0, 0, 0);
    buf ^= 1;
  }

  #pragma unroll
  for (int i = 0; i < NI; ++i) {
    #pragma unroll
    for (int q2 = 0; q2 < 4; ++q2) {
      int row = R0 + wm*(NI*16) + i*16 + g*4 + q2;
      bool rok = row < BN;
      if (MODE == 0) {
        if (!rok) continue;
        int b2 = row / N, n2 = row - b2*N;
        #pragma unroll
        for (int j = 0; j < 4; ++j) {
          int o = wn*64 + j*16 + fr;
          float gv = acc[i][j][q2] + bias[by*128 + o];
          float sg = 1.f/(1.f + expf(-gv));
          if (by == 0) {
            float rv = sg * hx[(size_t)row*RUNITS + o];
            if (o < 127) {
              mB0[(size_t)n2*MS + b2*128 + o + 1] = f8(rv);
            } else {
              xtw[((size_t)n2*4 + b2)*16 + 8] = f2bf(rv);
              tl8[(size_t)(8*4 + b2)*N + n2] = f8(rv);
            }
            if (o == 0) mB0[(size_t)n2*MS + b2*128] = f8(inp[row]);
          } else {
            ub[(size_t)row*RUNITS + o] = f2bf(sg);
          }
        }
      } else {
        float pj = 0.f;
        #pragma unroll
        for (int j = 0; j < 4; ++j) {
          int o = wn*64 + j*16 + fr;
          float gv = acc[i][j][q2] + bias[o];
          float cv = tanhf(gv);
          if (rok) {
            float uu = bf2f(ub[(size_t)row*RUNITS + o]);
            float hh = hx[(size_t)row*RUNITS + o];
            float nh = uu*hh + (1.f - uu)*cv;
            outh[(size_t)row*RUNITS + o] = nh;
            pj += nh * wpj[o];
          }
        }
        #pragma unroll
        for (int d = 1; d < 16; d <<= 1) pj += __shfl_xor(pj, d);
        if (rok && fr == 0) pjl[row - R0][wn] = pj;
      }
    }
  }
  if (MODE == 1) {
    __syncthreads();
    if (tid < TM) {
      int row = R0 + tid;
      if (row < BN) outy[row] = pjl[tid][0] + pjl[tid][1] + bpj[0];
    }
  }
}

// ---------------- launcher ----------------

extern "C" void kernel_launch(void* const* d_in, const int* in_sizes, int n_in,
                              void* d_out, int out_size, void* d_ws, size_t ws_size,
                              hipStream_t stream) {
  const float* inputs = (const float*)d_in[0];
  const float* hidden = (const float*)d_in[1];
  const int*   esrc   = (const int*)d_in[2];
  const int*   edst   = (const int*)d_in[3];
  const float* ew     = (const float*)d_in[4];
  const float* Wg     = (const float*)d_in[5];
  const float* bg     = (const float*)d_in[6];
  const float* Wc     = (const float*)d_in[7];
  const float* bc     = (const float*)d_in[8];
  const float* Wpj    = (const float*)d_in[9];
  const float* bpj    = (const float*)d_in[10];

  const int N  = in_sizes[0] / BATCH;
  const int E  = in_sizes[2];
  const int BN = BATCH * N;

  char* p = (char*)d_ws;
  auto alloc = [&](size_t bytes) -> void* {
    void* r = (void*)p;
    p += (bytes + 255) & ~(size_t)255;
    return r;
  };

  float* deg_out = (float*)alloc((size_t)4*N*sizeof(float));
  float* deg_in  = deg_out + N;
  int*   cnt_f   = (int*)(deg_out + 2*(size_t)N);
  int*   cnt_b   = cnt_f + N;
  int*   ptr_f   = (int*)alloc((size_t)(N+1)*sizeof(int));
  int*   ptr_b   = (int*)alloc((size_t)(N+1)*sizeof(int));
  int*   cur_f   = (int*)alloc((size_t)N*sizeof(int));
  int*   cur_b   = (int*)alloc((size_t)N*sizeof(int));
  int*   col_f   = (int*)alloc((size_t)E*sizeof(int));
  int*   col_b   = (int*)alloc((size_t)E*sizeof(int));
  float* val_f   = (float*)alloc((size_t)E*sizeof(float));
  float* val_b   = (float*)alloc((size_t)E*sizeof(float));
  int*   bsum    = (int*)alloc(80*sizeof(int));
  int*   bofs    = (int*)alloc(80*sizeof(int));
  ushort16* WtG  = (ushort16*)alloc((size_t)2*RUNITS*KB*sizeof(ushort16));
  ushort16* WtC  = (ushort16*)alloc((size_t)RUNITS*KB*sizeof(ushort16));
  uchar* mlv     = (uchar*)alloc((size_t)6*N*MS);   // slots 0..5
  ushort16* xtail= (ushort16*)alloc((size_t)N*4*16*sizeof(ushort16));
  uchar* tl8     = (uchar*)alloc((size_t)16*4*N);
  ushort16* ub   = (ushort16*)alloc((size_t)BN*RUNITS*sizeof(ushort16));

  float* out_y = (float*)d_out;
  float* out_h = out_y + BN;

  const size_t lvls = (size_t)N*MS;
  uchar* mA0 = mlv;
  uchar* m1  = mlv + 1*lvls;
  uchar* m2  = mlv + 2*lvls;
  uchar* m3  = mlv + 3*lvls;
  uchar* m4  = mlv + 4*lvls;
  uchar* mB0 = mlv + 5*lvls;

  const int TB = 256;
  int nb = (N + 255)/256;
  int sgrid = (N + 3) / 4;
  int packb = (3*RUNITS*KB + TB - 1) / TB;
  int gx64 = (BN + 63) / 64;
  int gx32 = (BN + 31) / 32;

  k_zero_i<<<(4*N+TB-1)/TB, TB, 0, stream>>>((int*)deg_out, 4*N);
  // fused build_x0 + weight pack (independent work, one launch)
  k_bx0pack<<<sgrid + packb, TB, 0, stream>>>(
      inputs, hidden, mA0, xtail, tl8, Wg, Wc, WtG, WtC, N, sgrid);
  k_deg_cnt<<<(E+TB-1)/TB, TB, 0, stream>>>(esrc, edst, ew, E, deg_out, deg_in, cnt_f, cnt_b);
  k_scansum<<<dim3(nb,2), TB, 0, stream>>>(cnt_f, cnt_b, bsum, N);
  k_scanmid<<<1, 64, 0, stream>>>(bsum, bofs, ptr_f, ptr_b, N, nb);
  k_scanapply<<<dim3(nb,2), TB, 0, stream>>>(cnt_f, cnt_b, bofs, ptr_f, cur_f, ptr_b, cur_b, N);
  k_fill<<<(E+TB-1)/TB, TB, 0, stream>>>(esrc, edst, ew, E, deg_out, deg_in,
                                         cur_f, cur_b, col_f, val_f, col_b, val_b);

  // ---- gates gconv ----
  k_spmm2<false><<<2*sgrid, TB, 0, stream>>>(
      ptr_f, col_f, val_f, ptr_b, col_b, val_b,
      mA0, mA0, m1, m3, mA0, xtail, tl8,
      0, 0, 1, 3, 0, N, sgrid, 1.f, 0.f);
  k_spmm2<true><<<2*sgrid, TB, 0, stream>>>(
      ptr_f, col_f, val_f, ptr_b, col_b, val_b,
      m1, m3, m2, m4, mA0, xtail, tl8,
      1, 3, 2, 4, 0, N, sgrid, 2.f, -1.f);
  // gates GEMM: ub (by=1); mB0 = fp8 [x_in, r*hx] + tails (by=0)
  k_gemm<64, 0><<<dim3(gx64, 2), TB, 0, stream>>>(
      mlv, xtail, WtG, bg, hidden, inputs, mB0, xtail, tl8, ub,
      nullptr, nullptr, nullptr, nullptr, 0, N, BN);

  // ---- candidate gconv (level 0 = slot 5) ----
  k_spmm2<false><<<2*sgrid, TB, 0, stream>>>(
      ptr_f, col_f, val_f, ptr_b, col_b, val_b,
      mB0, mB0, m1, m3, mB0, xtail, tl8,
      8, 8, 9, 11, 8, N, sgrid, 1.f, 0.f);
  k_spmm2<true><<<2*sgrid, TB, 0, stream>>>(
      ptr_f, col_f, val_f, ptr_b, col_b, val_b,
      m1, m3, m2, m4, mB0, xtail, tl8,
      9, 11, 10, 12, 8, N, sgrid, 2.f, -1.f);
  k_gemm<32, 1><<<dim3(gx32, 1), TB, 0, stream>>>(
      mlv, xtail, WtC, bc, hidden, nullptr, nullptr, nullptr, nullptr, ub,
      out_h, out_y, Wpj, bpj, 5, N, BN);
}

// Round 21
// 310.054 us; speedup vs baseline: 1.0799x; 1.0033x over previous
//
#include <hip/hip_runtime.h>
#include <cstdint>
#include <cstddef>

#define BATCH  4
#define RUNITS 128
#define MM     5
#define SEG    128            // c per b-segment
#define MS     512            // fp8 mirror row stride bytes (4 segs x 128)
#define KB     672            // GEMM K: 20 steps (m*128+c) + 1 tail step

typedef unsigned int  uint32;
typedef unsigned char uchar;
typedef unsigned short ushort16;
typedef __attribute__((ext_vector_type(8))) short short8;
typedef __attribute__((ext_vector_type(4))) float f32x4;
typedef __attribute__((ext_vector_type(2))) float f32x2;

__device__ inline ushort16 f2bf(float f){
  uint32 u = __float_as_uint(f);
  return (ushort16)((u + 0x7FFFu + ((u >> 16) & 1u)) >> 16);
}
__device__ inline float bf2f(ushort16 v){ return __uint_as_float(((uint32)v) << 16); }
__device__ inline int sw4(int r){ return (r ^ (r >> 2)) & 3; }

__device__ inline uint32 pk4f8(float a, float b, float c, float d){
  uint32 w = __builtin_amdgcn_cvt_pk_fp8_f32(a, b, 0u, false);
  w = __builtin_amdgcn_cvt_pk_fp8_f32(c, d, w, true);
  return w;
}
__device__ inline uchar f8(float a){
  return (uchar)(__builtin_amdgcn_cvt_pk_fp8_f32(a, 0.f, 0u, false) & 0xFFu);
}
// packed f32 pair -> 2x bf16 (RNE), single HW instruction
__device__ inline uint32 pkbf16(float lo, float hi){
  uint32 r;
  asm volatile("v_cvt_pk_bf16_f32 %0, %1, %2" : "=v"(r) : "v"(lo), "v"(hi));
  return r;
}
__device__ inline uint4 f8x8_to_bf8(uint2 u8){
  f32x2 p0 = __builtin_amdgcn_cvt_pk_f32_fp8(u8.x, false);
  f32x2 p1 = __builtin_amdgcn_cvt_pk_f32_fp8(u8.x, true);
  f32x2 p2 = __builtin_amdgcn_cvt_pk_f32_fp8(u8.y, false);
  f32x2 p3 = __builtin_amdgcn_cvt_pk_f32_fp8(u8.y, true);
  uint4 r;
  r.x = pkbf16(p0.x, p0.y); r.y = pkbf16(p1.x, p1.y);
  r.z = pkbf16(p2.x, p2.y); r.w = pkbf16(p3.x, p3.y);
  return r;
}

// async global -> LDS, 16B/lane
__device__ inline void gld16(const void* g, void* l) {
  __builtin_amdgcn_global_load_lds(
      (const __attribute__((address_space(1))) unsigned int*)g,
      (__attribute__((address_space(3))) unsigned int*)l, 16, 0, 0);
}

// ---------------- graph prep ----------------

__global__ void k_zero_i(int* p, int n) {
  int i = blockIdx.x*blockDim.x + threadIdx.x;
  if (i < n) p[i] = 0;
}

__global__ void k_deg_cnt(const int* __restrict__ src, const int* __restrict__ dst,
                          const float* __restrict__ w, int E,
                          float* deg_out, float* deg_in, int* cnt_f, int* cnt_b) {
  int e = blockIdx.x*blockDim.x + threadIdx.x;
  if (e >= E) return;
  int s = src[e], d = dst[e]; float we = w[e];
  atomicAdd(&deg_out[s], we);
  atomicAdd(&deg_in[d], we);
  atomicAdd(&cnt_f[s], 1);
  atomicAdd(&cnt_b[d], 1);
}

__global__ __launch_bounds__(256) void k_scansum(
    const int* __restrict__ cnt_f, const int* __restrict__ cnt_b, int* bsum, int n) {
  const int* cnt = blockIdx.y ? cnt_b : cnt_f;
  int tid = threadIdx.x, lane = tid & 63, wv = tid >> 6;
  int i = blockIdx.x*256 + tid;
  int v = (i < n) ? cnt[i] : 0;
  #pragma unroll
  for (int d = 32; d > 0; d >>= 1) v += __shfl_down(v, d);
  __shared__ int sm[4];
  if (lane == 0) sm[wv] = v;
  __syncthreads();
  if (tid == 0) bsum[blockIdx.y*40 + blockIdx.x] = sm[0]+sm[1]+sm[2]+sm[3];
}

__global__ __launch_bounds__(64) void k_scanmid(
    const int* bsum, int* bofs, int* ptrF, int* ptrB, int n, int nb) {
  int lane = threadIdx.x;
  for (int a = 0; a < 2; ++a) {
    int v = (lane < nb) ? bsum[a*nb + lane] : 0;
    int x = v;
    #pragma unroll
    for (int d = 1; d < 64; d <<= 1) { int t = __shfl_up(x, d); if (lane >= d) x += t; }
    if (lane < nb) bofs[a*nb + lane] = x - v;
    if (lane == nb - 1) { if (a) ptrB[n] = x; else ptrF[n] = x; }
  }
}

__global__ __launch_bounds__(256) void k_scanapply(
    const int* __restrict__ cnt_f, const int* __restrict__ cnt_b, const int* __restrict__ bofs,
    int* ptrF, int* curF, int* ptrB, int* curB, int n) {
  int a = blockIdx.y;
  const int* cnt = a ? cnt_b : cnt_f;
  int* ptr = a ? ptrB : ptrF;
  int* cur = a ? curB : curF;
  int tid = threadIdx.x, lane = tid & 63, wv = tid >> 6;
  int i = blockIdx.x*256 + tid;
  int v = (i < n) ? cnt[i] : 0;
  int x = v;
  #pragma unroll
  for (int d = 1; d < 64; d <<= 1) { int t = __shfl_up(x, d); if (lane >= d) x += t; }
  __shared__ int ws[4];
  __shared__ int wo[4];
  if (lane == 63) ws[wv] = x;
  __syncthreads();
  if (tid == 0) { int s = 0; for (int k = 0; k < 4; ++k) { wo[k] = s; s += ws[k]; } }
  __syncthreads();
  int excl = x - v + wo[wv] + bofs[a*40 + blockIdx.x];
  if (i < n) { ptr[i] = excl; cur[i] = excl; }
}

__global__ void k_fill(const int* __restrict__ src, const int* __restrict__ dst,
                       const float* __restrict__ w, int E,
                       const float* __restrict__ deg_out, const float* __restrict__ deg_in,
                       int* cur_f, int* cur_b,
                       int* col_f, float* val_f, int* col_b, float* val_b) {
  int e = blockIdx.x*blockDim.x + threadIdx.x;
  if (e >= E) return;
  int s = src[e], d = dst[e]; float we = w[e];
  int pf = atomicAdd(&cur_f[s], 1);
  col_f[pf] = d; val_f[pf] = we / deg_out[s];
  int pb = atomicAdd(&cur_b[d], 1);
  col_b[pb] = s; val_b[pb] = we / deg_in[d];
}

// ---------------- fused: build x0 (blocks < sgrid) + weight pack (rest) ----------------

__global__ __launch_bounds__(256) void k_bx0pack(
    const float* __restrict__ inp, const float* __restrict__ hf,
    uchar* __restrict__ mA0, ushort16* __restrict__ xtail, uchar* __restrict__ tl8,
    const float* __restrict__ Wg, const float* __restrict__ Wc,
    ushort16* __restrict__ WtG, ushort16* __restrict__ WtC,
    int N, int sgrid) {
  if (blockIdx.x < (unsigned)sgrid) {
    int wv = threadIdx.x >> 6, lane = threadIdx.x & 63;
    int n = blockIdx.x*4 + wv;
    if (n >= N) return;
    int b = lane >> 4, ch = lane & 15;
    size_t r = (size_t)b*N + n;
    size_t hbase = r*RUNITS;
    float fv[8];
    if (ch == 0) {
      fv[0] = inp[r];
      #pragma unroll
      for (int s = 1; s < 8; ++s) fv[s] = hf[hbase + s - 1];
    } else {
      int c0 = ch*8 - 1;
      #pragma unroll
      for (int s = 0; s < 8; ++s) fv[s] = hf[hbase + c0 + s];
    }
    uint2 mv;
    mv.x = pk4f8(fv[0], fv[1], fv[2], fv[3]);
    mv.y = pk4f8(fv[4], fv[5], fv[6], fv[7]);
    *(uint2*)(mA0 + (size_t)n*MS + b*128 + ch*8) = mv;
    if (ch == 15) {
      float h127 = hf[hbase + 127];
      xtail[((size_t)n*4 + b)*16 + 0] = f2bf(h127);
      tl8[(size_t)(0*4 + b)*N + n] = f8(h127);
    }
  } else {
    int idx = (blockIdx.x - sgrid)*256 + threadIdx.x;
    const int tg = 2*RUNITS*KB;
    const int tc = RUNITS*KB;
    if (idx >= tg + tc) return;
    const float* W; ushort16* Wt; int ncol;
    if (idx < tg) { W = Wg; Wt = WtG; ncol = 2*RUNITS; }
    else { idx -= tg; W = Wc; Wt = WtC; ncol = RUNITS; }
    int o = idx / KB, k = idx - o*KB;
    float v = 0.f;
    if (k < 640) {
      int m = k >> 7, c = k & 127;
      v = W[(size_t)(c*MM + m)*ncol + o];
    } else if (k < 645) {
      v = W[(size_t)k*ncol + o];
    }
    Wt[idx] = f2bf(v);
  }
}

// ---------------- full-wave dual SPMM over fp8 mirrors (fp8 in, fp8 out) ----------------

template<bool HY>
__global__ __launch_bounds__(256) void k_spmm2(
    const int* __restrict__ ptrF, const int* __restrict__ colF, const float* __restrict__ valF,
    const int* __restrict__ ptrB, const int* __restrict__ colB, const float* __restrict__ valB,
    const uchar* __restrict__ minF, const uchar* __restrict__ minB,
    uchar* __restrict__ moutF, uchar* __restrict__ moutB,
    const uchar* __restrict__ mY0, ushort16* __restrict__ xtail,
    uchar* __restrict__ tl8,
    int tinF, int tinB, int toutF, int toutB, int tz,
    int N, int sgrid, float alpha, float beta) {
  int bid = blockIdx.x;
  bool jb = bid >= sgrid;
  const int* ptr = jb ? ptrB : ptrF;
  const int* col = jb ? colB : colF;
  const float* val = jb ? valB : valF;
  const uchar* M = jb ? minB : minF;
  uchar* mout = jb ? moutB : moutF;
  int tin = jb ? tinB : tinF;
  int tout = jb ? toutB : toutF;
  int wv = threadIdx.x >> 6, lane = threadIdx.x & 63;
  int n = (bid - (jb ? sgrid : 0))*4 + wv;
  if (n >= N) return;
  int s = ptr[n], e = ptr[n+1];
  bool tq = lane < 4;
  const uchar* tlin = tl8 + (size_t)(tin*4 + lane)*N;
  float a[8] = {0.f,0.f,0.f,0.f,0.f,0.f,0.f,0.f};
  float at = 0.f;
  #pragma unroll 8
  for (int i = s; i < e; ++i) {
    int cl = col[i]; float v = val[i];
    uint2 u = *(const uint2*)(M + (size_t)cl*MS + lane*8);
    f32x2 p0 = __builtin_amdgcn_cvt_pk_f32_fp8(u.x, false);
    f32x2 p1 = __builtin_amdgcn_cvt_pk_f32_fp8(u.x, true);
    f32x2 p2 = __builtin_amdgcn_cvt_pk_f32_fp8(u.y, false);
    f32x2 p3 = __builtin_amdgcn_cvt_pk_f32_fp8(u.y, true);
    a[0] += v*p0.x; a[1] += v*p0.y;
    a[2] += v*p1.x; a[3] += v*p1.y;
    a[4] += v*p2.x; a[5] += v*p2.y;
    a[6] += v*p3.x; a[7] += v*p3.y;
    if (tq) {
      uint32 tb = tlin[cl];
      at += v * __builtin_amdgcn_cvt_f32_fp8(tb, 0);
    }
  }
  float r[8];
  if (HY) {
    uint2 y8 = *(const uint2*)(mY0 + (size_t)n*MS + lane*8);
    f32x2 y0 = __builtin_amdgcn_cvt_pk_f32_fp8(y8.x, false);
    f32x2 y1 = __builtin_amdgcn_cvt_pk_f32_fp8(y8.x, true);
    f32x2 y2 = __builtin_amdgcn_cvt_pk_f32_fp8(y8.y, false);
    f32x2 y3 = __builtin_amdgcn_cvt_pk_f32_fp8(y8.y, true);
    r[0] = alpha*a[0] + beta*y0.x; r[1] = alpha*a[1] + beta*y0.y;
    r[2] = alpha*a[2] + beta*y1.x; r[3] = alpha*a[3] + beta*y1.y;
    r[4] = alpha*a[4] + beta*y2.x; r[5] = alpha*a[5] + beta*y2.y;
    r[6] = alpha*a[6] + beta*y3.x; r[7] = alpha*a[7] + beta*y3.y;
  } else {
    #pragma unroll
    for (int k = 0; k < 8; ++k) r[k] = alpha*a[k];
  }
  uint2 mv;
  mv.x = pk4f8(r[0], r[1], r[2], r[3]);
  mv.y = pk4f8(r[4], r[5], r[6], r[7]);
  *(uint2*)(mout + (size_t)n*MS + lane*8) = mv;
  if (tq) {
    float rt = alpha*at;
    if (HY) rt += beta * bf2f(xtail[((size_t)n*4 + lane)*16 + tz]);
    xtail[((size_t)n*4 + lane)*16 + tout] = f2bf(rt);
    tl8[(size_t)(tout*4 + lane)*N + n] = f8(rt);
  }
}

// ---------------- unified MFMA GEMM (all-fp8 A; B via global_load_lds) ----------------
// mlv: 6 mirror slots (stride N*MS): 0 = gconv1 level0, 1..4 = diffusion levels,
// 5 = gconv2 level0. A staged per step: fp8 load -> cvt (v_cvt_pk_bf16_f32) ->
// swizzled ds_write. MODE 0 (gates, grid.y=2): sigmoid; by=0 -> r*hx into slot5 +
// tails; by=1 -> ub. MODE 1 (cand, l0slot=5): tanh + GRU combine + fused projection.

template<int TM, int MODE>
__global__ __launch_bounds__(256, 5) void k_gemm(
    const uchar* __restrict__ mlv, const ushort16* __restrict__ xtail,
    const ushort16* __restrict__ Bt, const float* __restrict__ bias,
    const float* __restrict__ hx, const float* __restrict__ inp,
    uchar* __restrict__ mB0, ushort16* __restrict__ xtw, uchar* __restrict__ tl8,
    ushort16* __restrict__ ub, float* __restrict__ outh,
    float* __restrict__ outy, const float* __restrict__ wpj,
    const float* __restrict__ bpj, int l0slot, int N, int BN) {
  constexpr int NI = TM / 32;
  __shared__ __align__(16) ushort16 As[2][TM*32];
  __shared__ __align__(16) ushort16 Bs[2][128*32];
  __shared__ float pjl[TM][2];
  int tid = threadIdx.x, lane = tid & 63, wv = tid >> 6;
  int wm = wv >> 1, wn = wv & 1;
  int fr = lane & 15, g = lane >> 4;
  int R0 = blockIdx.x*TM, by = blockIdx.y;
  const size_t lvls = (size_t)N*MS;

  // --- A reg staging mapping (one chunk per thread) ---
  int rA = tid >> 2, p = tid & 3;
  bool aact = (TM == 64) || (tid < TM*4);
  int sa = p ^ sw4(rA);
  int gr = R0 + rA; if (gr >= BN) gr = BN - 1;
  int bA = gr / N, nA = gr - bA*N;
  const uchar* aAnchor = mlv + (size_t)nA*MS + bA*128;
  const uchar* aM0 = aAnchor + (size_t)l0slot*lvls;
  const ushort16* tBase = xtail + ((size_t)nA*4 + bA)*16 + (MODE == 1 ? 8 : 0);
  int aofs = rA*32 + (p << 3);

  // --- B gload mapping: 2 instrs/wave, lane -> slot (col,pos) ---
  int colB0 = (wv*2 + 0)*16 + (lane >> 2);
  int colB1 = (wv*2 + 1)*16 + (lane >> 2);
  int posB  = lane & 3;
  const ushort16* bG0 = Bt + (size_t)(by*128 + colB0)*KB + (posB ^ sw4(colB0))*8;
  const ushort16* bG1 = Bt + (size_t)(by*128 + colB1)*KB + (posB ^ sw4(colB1))*8;

  f32x4 acc[NI][4];
  #pragma unroll
  for (int i = 0; i < NI; ++i)
    #pragma unroll
    for (int j = 0; j < 4; ++j) acc[i][j] = (f32x4){0.f,0.f,0.f,0.f};

  auto stageB = [&](int s, int bb) {
    gld16(bG0 + 4*s*8, &Bs[bb][(wv*2 + 0)*512]);
    gld16(bG1 + 4*s*8, &Bs[bb][(wv*2 + 1)*512]);
  };
  auto stageA = [&](int s, int bb) {
    if (!aact) return;
    if (s < 20) {
      int m = s >> 2;
      const uchar* base = (m == 0) ? aM0 : (aAnchor + (size_t)m*lvls);
      int ch = (4*s + sa) & 15;
      *(uint4*)&As[bb][aofs] = f8x8_to_bf8(*(const uint2*)(base + ch*8));
    } else {
      if (sa == 0) *(uint4*)&As[bb][aofs] = *(const uint4*)tBase;
    }
  };

  stageA(0, 0);
  stageB(0, 0);

  int buf = 0;
  for (int s = 0; s < 21; ++s) {
    __syncthreads();
    if (s < 20) { stageB(s + 1, buf ^ 1); stageA(s + 1, buf ^ 1); }
    short8 af[NI], bfv[4];
    #pragma unroll
    for (int i = 0; i < NI; ++i) {
      int rr = wm*(NI*16) + i*16 + fr;
      af[i] = *(const short8*)&As[buf][rr*32 + ((g ^ sw4(rr)) << 3)];
    }
    #pragma unroll
    for (int j = 0; j < 4; ++j) {
      int cc = wn*64 + j*16 + fr;
      bfv[j] = *(const short8*)&Bs[buf][cc*32 + ((g ^ sw4(cc)) << 3)];
    }
    #pragma unroll
    for (int i = 0; i < NI; ++i)
      #pragma unroll
      for (int j = 0; j < 4; ++j)
        acc[i][j] = __builtin_amdgcn_mfma_f32_16x16x32_bf16(af[i], bfv[j], acc[i][j], 0, 0, 0);
    buf ^= 1;
  }

  #pragma unroll
  for (int i = 0; i < NI; ++i) {
    #pragma unroll
    for (int q2 = 0; q2 < 4; ++q2) {
      int row = R0 + wm*(NI*16) + i*16 + g*4 + q2;
      bool rok = row < BN;
      if (MODE == 0) {
        if (!rok) continue;
        int b2 = row / N, n2 = row - b2*N;
        #pragma unroll
        for (int j = 0; j < 4; ++j) {
          int o = wn*64 + j*16 + fr;
          float gv = acc[i][j][q2] + bias[by*128 + o];
          float sg = 1.f/(1.f + expf(-gv));
          if (by == 0) {
            float rv = sg * hx[(size_t)row*RUNITS + o];
            if (o < 127) {
              mB0[(size_t)n2*MS + b2*128 + o + 1] = f8(rv);
            } else {
              xtw[((size_t)n2*4 + b2)*16 + 8] = f2bf(rv);
              tl8[(size_t)(8*4 + b2)*N + n2] = f8(rv);
            }
            if (o == 0) mB0[(size_t)n2*MS + b2*128] = f8(inp[row]);
          } else {
            ub[(size_t)row*RUNITS + o] = f2bf(sg);
          }
        }
      } else {
        float pj = 0.f;
        #pragma unroll
        for (int j = 0; j < 4; ++j) {
          int o = wn*64 + j*16 + fr;
          float gv = acc[i][j][q2] + bias[o];
          float cv = tanhf(gv);
          if (rok) {
            float uu = bf2f(ub[(size_t)row*RUNITS + o]);
            float hh = hx[(size_t)row*RUNITS + o];
            float nh = uu*hh + (1.f - uu)*cv;
            outh[(size_t)row*RUNITS + o] = nh;
            pj += nh * wpj[o];
          }
        }
        #pragma unroll
        for (int d = 1; d < 16; d <<= 1) pj += __shfl_xor(pj, d);
        if (rok && fr == 0) pjl[row - R0][wn] = pj;
      }
    }
  }
  if (MODE == 1) {
    __syncthreads();
    if (tid < TM) {
      int row = R0 + tid;
      if (row < BN) outy[row] = pjl[tid][0] + pjl[tid][1] + bpj[0];
    }
  }
}

// ---------------- launcher ----------------

extern "C" void kernel_launch(void* const* d_in, const int* in_sizes, int n_in,
                              void* d_out, int out_size, void* d_ws, size_t ws_size,
                              hipStream_t stream) {
  const float* inputs = (const float*)d_in[0];
  const float* hidden = (const float*)d_in[1];
  const int*   esrc   = (const int*)d_in[2];
  const int*   edst   = (const int*)d_in[3];
  const float* ew     = (const float*)d_in[4];
  const float* Wg     = (const float*)d_in[5];
  const float* bg     = (const float*)d_in[6];
  const float* Wc     = (const float*)d_in[7];
  const float* bc     = (const float*)d_in[8];
  const float* Wpj    = (const float*)d_in[9];
  const float* bpj    = (const float*)d_in[10];

  const int N  = in_sizes[0] / BATCH;
  const int E  = in_sizes[2];
  const int BN = BATCH * N;

  char* p = (char*)d_ws;
  auto alloc = [&](size_t bytes) -> void* {
    void* r = (void*)p;
    p += (bytes + 255) & ~(size_t)255;
    return r;
  };

  float* deg_out = (float*)alloc((size_t)4*N*sizeof(float));
  float* deg_in  = deg_out + N;
  int*   cnt_f   = (int*)(deg_out + 2*(size_t)N);
  int*   cnt_b   = cnt_f + N;
  int*   ptr_f   = (int*)alloc((size_t)(N+1)*sizeof(int));
  int*   ptr_b   = (int*)alloc((size_t)(N+1)*sizeof(int));
  int*   cur_f   = (int*)alloc((size_t)N*sizeof(int));
  int*   cur_b   = (int*)alloc((size_t)N*sizeof(int));
  int*   col_f   = (int*)alloc((size_t)E*sizeof(int));
  int*   col_b   = (int*)alloc((size_t)E*sizeof(int));
  float* val_f   = (float*)alloc((size_t)E*sizeof(float));
  float* val_b   = (float*)alloc((size_t)E*sizeof(float));
  int*   bsum    = (int*)alloc(80*sizeof(int));
  int*   bofs    = (int*)alloc(80*sizeof(int));
  ushort16* WtG  = (ushort16*)alloc((size_t)2*RUNITS*KB*sizeof(ushort16));
  ushort16* WtC  = (ushort16*)alloc((size_t)RUNITS*KB*sizeof(ushort16));
  uchar* mlv     = (uchar*)alloc((size_t)6*N*MS);   // slots 0..5
  ushort16* xtail= (ushort16*)alloc((size_t)N*4*16*sizeof(ushort16));
  uchar* tl8     = (uchar*)alloc((size_t)16*4*N);
  ushort16* ub   = (ushort16*)alloc((size_t)BN*RUNITS*sizeof(ushort16));

  float* out_y = (float*)d_out;
  float* out_h = out_y + BN;

  const size_t lvls = (size_t)N*MS;
  uchar* mA0 = mlv;
  uchar* m1  = mlv + 1*lvls;
  uchar* m2  = mlv + 2*lvls;
  uchar* m3  = mlv + 3*lvls;
  uchar* m4  = mlv + 4*lvls;
  uchar* mB0 = mlv + 5*lvls;

  const int TB = 256;
  int nb = (N + 255)/256;
  int sgrid = (N + 3) / 4;
  int packb = (3*RUNITS*KB + TB - 1) / TB;
  int gx64 = (BN + 63) / 64;
  int gx32 = (BN + 31) / 32;

  k_zero_i<<<(4*N+TB-1)/TB, TB, 0, stream>>>((int*)deg_out, 4*N);
  // fused build_x0 + weight pack (independent work, one launch)
  k_bx0pack<<<sgrid + packb, TB, 0, stream>>>(
      inputs, hidden, mA0, xtail, tl8, Wg, Wc, WtG, WtC, N, sgrid);
  k_deg_cnt<<<(E+TB-1)/TB, TB, 0, stream>>>(esrc, edst, ew, E, deg_out, deg_in, cnt_f, cnt_b);
  k_scansum<<<dim3(nb,2), TB, 0, stream>>>(cnt_f, cnt_b, bsum, N);
  k_scanmid<<<1, 64, 0, stream>>>(bsum, bofs, ptr_f, ptr_b, N, nb);
  k_scanapply<<<dim3(nb,2), TB, 0, stream>>>(cnt_f, cnt_b, bofs, ptr_f, cur_f, ptr_b, cur_b, N);
  k_fill<<<(E+TB-1)/TB, TB, 0, stream>>>(esrc, edst, ew, E, deg_out, deg_in,
                                         cur_f, cur_b, col_f, val_f, col_b, val_b);

  // ---- gates gconv ----
  k_spmm2<false><<<2*sgrid, TB, 0, stream>>>(
      ptr_f, col_f, val_f, ptr_b, col_b, val_b,
      mA0, mA0, m1, m3, mA0, xtail, tl8,
      0, 0, 1, 3, 0, N, sgrid, 1.f, 0.f);
  k_spmm2<true><<<2*sgrid, TB, 0, stream>>>(
      ptr_f, col_f, val_f, ptr_b, col_b, val_b,
      m1, m3, m2, m4, mA0, xtail, tl8,
      1, 3, 2, 4, 0, N, sgrid, 2.f, -1.f);
  // gates GEMM: ub (by=1); mB0 = fp8 [x_in, r*hx] + tails (by=0)
  k_gemm<64, 0><<<dim3(gx64, 2), TB, 0, stream>>>(
      mlv, xtail, WtG, bg, hidden, inputs, mB0, xtail, tl8, ub,
      nullptr, nullptr, nullptr, nullptr, 0, N, BN);

  // ---- candidate gconv (level 0 = slot 5) ----
  k_spmm2<false><<<2*sgrid, TB, 0, stream>>>(
      ptr_f, col_f, val_f, ptr_b, col_b, val_b,
      mB0, mB0, m1, m3, mB0, xtail, tl8,
      8, 8, 9, 11, 8, N, sgrid, 1.f, 0.f);
  k_spmm2<true><<<2*sgrid, TB, 0, stream>>>(
      ptr_f, col_f, val_f, ptr_b, col_b, val_b,
      m1, m3, m2, m4, mB0, xtail, tl8,
      9, 11, 10, 12, 8, N, sgrid, 2.f, -1.f);
  k_gemm<32, 1><<<dim3(gx32, 1), TB, 0, stream>>>(
      mlv, xtail, WtC, bc, hidden, nullptr, nullptr, nullptr, nullptr, ub,
      out_h, out_y, Wpj, bpj, 5, N, BN);
}